// Round 1
// baseline (171.571 us; speedup 1.0000x reference)
//
#include <hip/hip_runtime.h>
#include <math.h>

#define N_RAYS    2048
#define N_SAMPLES 32
#define NPTS      (N_RAYS * N_SAMPLES)   // 65536
#define NV        6890

#define PARTS        4
#define PTS_PER_BLK  64
#define BLK          (PTS_PER_BLK * PARTS)  // 256
#define CHUNK        2048

// ---------------- Kernel A: invert 4x4 matrices (f64 Gauss-Jordan, partial pivot) ----------------
template <typename TOUT>
__global__ void invert_kernel(const float* __restrict__ Ts, TOUT* __restrict__ Tinv) {
    int v = blockIdx.x * blockDim.x + threadIdx.x;
    if (v >= NV) return;
    double a[4][8];
    #pragma unroll
    for (int i = 0; i < 4; ++i) {
        #pragma unroll
        for (int j = 0; j < 4; ++j) {
            a[i][j]     = (double)Ts[v * 16 + i * 4 + j];
            a[i][4 + j] = (i == j) ? 1.0 : 0.0;
        }
    }
    #pragma unroll
    for (int c = 0; c < 4; ++c) {
        // partial pivot
        int piv = c;
        double pv = fabs(a[c][c]);
        #pragma unroll
        for (int r = 0; r < 4; ++r) {
            if (r > c) {
                double t = fabs(a[r][c]);
                if (t > pv) { pv = t; piv = r; }
            }
        }
        if (piv != c) {
            #pragma unroll
            for (int j = 0; j < 8; ++j) { double t = a[c][j]; a[c][j] = a[piv][j]; a[piv][j] = t; }
        }
        double f = 1.0 / a[c][c];
        #pragma unroll
        for (int j = 0; j < 8; ++j) a[c][j] *= f;
        #pragma unroll
        for (int r = 0; r < 4; ++r) {
            if (r != c) {
                double g = a[r][c];
                #pragma unroll
                for (int j = 0; j < 8; ++j) a[r][j] -= g * a[c][j];
            }
        }
    }
    #pragma unroll
    for (int i = 0; i < 4; ++i)
        #pragma unroll
        for (int j = 0; j < 4; ++j)
            Tinv[v * 16 + i * 4 + j] = (TOUT)a[i][4 + j];
}

// ---------------- Kernel B: nearest-vertex scan + transform + finite-diff dirs ----------------
__device__ __forceinline__ double d2_f64(float px, float py, float pz,
                                         const float* __restrict__ verts, int idx) {
    double dx = (double)px - (double)verts[idx * 3 + 0];
    double dy = (double)py - (double)verts[idx * 3 + 1];
    double dz = (double)pz - (double)verts[idx * 3 + 2];
    return dx * dx + dy * dy + dz * dz;
}

template <typename TINV>
__global__ __launch_bounds__(BLK) void warp_kernel(
    const float* __restrict__ pts,      // NPTS*3
    const float* __restrict__ verts,    // NV*3
    const TINV* __restrict__ Tinv,      // NV*16
    float* __restrict__ out)            // 2*NPTS*3
{
    __shared__ float4 sv[CHUNK];
    __shared__ double scan[PTS_PER_BLK][3];

    const int part = threadIdx.x & (PARTS - 1);
    const int lp   = threadIdx.x >> 2;                 // local point 0..63
    const int n    = blockIdx.x * PTS_PER_BLK + lp;    // global point

    const float px = pts[n * 3 + 0];
    const float py = pts[n * 3 + 1];
    const float pz = pts[n * 3 + 2];

    float d1 = 3.4e38f, d2v = 3.4e38f;
    int   i1 = 0,       i2  = 0;

    for (int base = 0; base < NV; base += CHUNK) {
        int cnt = NV - base; if (cnt > CHUNK) cnt = CHUNK;
        __syncthreads();   // protect sv[] from readers of previous chunk
        for (int v = threadIdx.x; v < cnt; v += BLK) {
            float x = verts[(base + v) * 3 + 0];
            float y = verts[(base + v) * 3 + 1];
            float z = verts[(base + v) * 3 + 2];
            sv[v] = make_float4(x, y, z, fmaf(x, x, fmaf(y, y, z * z)));
        }
        __syncthreads();
        #pragma unroll 4
        for (int v = part; v < cnt; v += PARTS) {
            float4 q = sv[v];
            float  s = fmaf(px, q.x, fmaf(py, q.y, pz * q.z));
            float  d = fmaf(-2.0f, s, q.w);      // |v|^2 - 2 p.v  (same ordering as d2)
            int gi = base + v;
            if (d < d1)       { d2v = d1; i2 = i1; d1 = d; i1 = gi; }
            else if (d < d2v) { d2v = d;  i2 = gi; }
        }
    }

    // merge the 4 partial (best, second-best) across parts; tie-break on smaller index
    #pragma unroll
    for (int off = 1; off < PARTS; off <<= 1) {
        float od1 = __shfl_xor(d1, off);
        int   oi1 = __shfl_xor(i1, off);
        float od2 = __shfl_xor(d2v, off);
        int   oi2 = __shfl_xor(i2, off);
        bool bless = (od1 < d1) || (od1 == d1 && oi1 < i1);
        float w1 = bless ? od1 : d1;   int wi1 = bless ? oi1 : i1;     // winner first
        float lf = bless ? d1  : od1;  int lfi = bless ? i1  : oi1;    // loser first
        float ws = bless ? od2 : d2v;  int wsi = bless ? oi2 : i2;     // winner's second
        bool c2 = (lf < ws) || (lf == ws && lfi < wsi);
        d1 = w1; i1 = wi1;
        d2v = c2 ? lf : ws; i2 = c2 ? lfi : wsi;
    }

    // f64 refinement for near-ties (true argmin; matches a float64 numpy reference)
    if (d2v - d1 < 1e-4f) {
        double e1 = d2_f64(px, py, pz, verts, i1);
        double e2 = d2_f64(px, py, pz, verts, i2);
        if (e2 < e1 || (e2 == e1 && i2 < i1)) i1 = i2;
    }

    if (part == 0) {
        const TINV* T = Tinv + (size_t)i1 * 16;
        double hx = -(double)px, hy = -(double)py, hz = (double)pz;
        double c0 = (double)T[0] * hx + (double)T[1] * hy + (double)T[2]  * hz + (double)T[3];
        double c1 = (double)T[4] * hx + (double)T[5] * hy + (double)T[6]  * hz + (double)T[7];
        double c2 = (double)T[8] * hx + (double)T[9] * hy + (double)T[10] * hz + (double)T[11];
        // flipped canonical point (can * [-1,-1,1])
        double f0 = -c0, f1 = -c1, f2 = c2;
        scan[lp][0] = f0; scan[lp][1] = f1; scan[lp][2] = f2;
        out[n * 3 + 0] = (float)f0;
        out[n * 3 + 1] = (float)f1;
        out[n * 3 + 2] = (float)f2;
    }
    __syncthreads();

    if (part == 0) {
        // finite diff along samples; block = 64 points = exactly 2 rays, so all in LDS
        int s  = n & (N_SAMPLES - 1);
        int l0 = lp, l1 = lp + 1;
        if (s == N_SAMPLES - 1) { l0 = lp - 1; l1 = lp; }
        double dx = scan[l1][0] - scan[l0][0];
        double dy = scan[l1][1] - scan[l0][1];
        double dz = scan[l1][2] - scan[l0][2];
        double nr = sqrt(dx * dx + dy * dy + dz * dz);
        nr = fmax(nr, 1e-12);
        float* o = out + (size_t)NPTS * 3 + (size_t)n * 3;
        o[0] = (float)(dx / nr);
        o[1] = (float)(dy / nr);
        o[2] = (float)(dz / nr);
    }
}

// ---------------- launch ----------------
extern "C" void kernel_launch(void* const* d_in, const int* in_sizes, int n_in,
                              void* d_out, int out_size, void* d_ws, size_t ws_size,
                              hipStream_t stream) {
    const float* pts   = (const float*)d_in[0];   // rays_points_world
    // d_in[1] (rays_directions_world) unused by the reference computation
    const float* verts = (const float*)d_in[2];   // vertices_posed
    const float* Ts    = (const float*)d_in[3];   // Ts
    float* out = (float*)d_out;

    const int invBlocks = (NV + 255) / 256;
    const int mainBlocks = NPTS / PTS_PER_BLK;    // 1024

    if (ws_size >= (size_t)NV * 16 * sizeof(double)) {
        double* Tinv = (double*)d_ws;
        hipLaunchKernelGGL((invert_kernel<double>), dim3(invBlocks), dim3(256), 0, stream, Ts, Tinv);
        hipLaunchKernelGGL((warp_kernel<double>), dim3(mainBlocks), dim3(BLK), 0, stream,
                           pts, verts, Tinv, out);
    } else {
        float* Tinv = (float*)d_ws;
        hipLaunchKernelGGL((invert_kernel<float>), dim3(invBlocks), dim3(256), 0, stream, Ts, Tinv);
        hipLaunchKernelGGL((warp_kernel<float>), dim3(mainBlocks), dim3(BLK), 0, stream,
                           pts, verts, Tinv, out);
    }
}

// Round 2
// 114.377 us; speedup vs baseline: 1.5000x; 1.5000x over previous
//
#include <hip/hip_runtime.h>
#include <math.h>
#include <stdint.h>

#define N_RAYS    2048
#define N_SAMPLES 32
#define NPTS      (N_RAYS * N_SAMPLES)   // 65536
#define NV        6890
#define CHUNK     2048
#define QMASK     0xFFFFE000u            // keep exponent + 10 mantissa bits
#define IMASK     0x1FFFu                // 13-bit vertex index (NV < 8192)

// ws layout: [0..4) u32 flag count | [64..64+2*NPTS) u16 idx | [..+2*NPTS) u16 flag list
#define WS_IDX_OFF   64
#define WS_LIST_OFF  (64 + 2 * NPTS)
#define WS_BYTES     (64 + 4 * NPTS)     // 262208

__global__ void init_kernel(uint32_t* __restrict__ count) {
    if (threadIdx.x == 0) *count = 0;
}

// ---- K2: brute-force nearest-vertex scan, packed-key tracking -------------
// Layout: 256 thr/block; thread = (grp 0..31, part 0..7); each (grp) owns 2
// points, the 8 parts split vertices v ≡ part (mod 8). 1024 blocks.
__global__ __launch_bounds__(256) void scan_kernel(
    const float* __restrict__ pts, const float* __restrict__ verts,
    uint16_t* __restrict__ idx16, uint16_t* __restrict__ list16,
    uint32_t* __restrict__ count)
{
    __shared__ float4 sv[CHUNK];
    const int tid  = threadIdx.x;
    const int part = tid & 7;
    const int grp  = tid >> 3;                  // 0..31
    const int n0   = blockIdx.x * 64 + grp * 2; // two points: n0, n0+1

    const float ax = pts[n0*3+0], ay = pts[n0*3+1], az = pts[n0*3+2];
    const float bx = pts[n0*3+3], by = pts[n0*3+4], bz = pts[n0*3+5];
    // fold -|p|^2/2 into the dot chain so d = |p-v|^2 >= 0 (uint-sortable bits)
    const float acc = -0.5f * fmaf(ax, ax, fmaf(ay, ay, az*az));
    const float bcc = -0.5f * fmaf(bx, bx, fmaf(by, by, bz*bz));

    uint32_t ak1 = ~0u, ak2 = ~0u, bk1 = ~0u, bk2 = ~0u;

    for (int base = 0; base < NV; base += CHUNK) {
        const int cnt = min(NV - base, CHUNK);
        __syncthreads();
        for (int v = tid; v < cnt; v += 256) {
            const float x = verts[(base+v)*3+0];
            const float y = verts[(base+v)*3+1];
            const float z = verts[(base+v)*3+2];
            sv[v] = make_float4(x, y, z, fmaf(x, x, fmaf(y, y, z*z)));
        }
        __syncthreads();
        #pragma unroll 4
        for (int v = part; v < cnt; v += 8) {
            const float4 q = sv[v];
            const uint32_t vi = (uint32_t)(base + v);
            float s, d; uint32_t k;
            s = fmaf(ax, q.x, fmaf(ay, q.y, fmaf(az, q.z, acc)));
            d = fmaxf(fmaf(-2.f, s, q.w), 0.f);       // |p-v|^2, clamped >= 0
            k = (__float_as_uint(d) & QMASK) | vi;    // v_and_or_b32
            ak2 = min(ak2, max(ak1, k)); ak1 = min(ak1, k);
            s = fmaf(bx, q.x, fmaf(by, q.y, fmaf(bz, q.z, bcc)));
            d = fmaxf(fmaf(-2.f, s, q.w), 0.f);
            k = (__float_as_uint(d) & QMASK) | vi;
            bk2 = min(bk2, max(bk1, k)); bk1 = min(bk1, k);
        }
    }
    // merge the 8 parts' (min, 2nd-min) keys within the wave
    #pragma unroll
    for (int off = 1; off < 8; off <<= 1) {
        uint32_t o1, o2;
        o1 = (uint32_t)__shfl_xor((int)ak1, off);
        o2 = (uint32_t)__shfl_xor((int)ak2, off);
        ak2 = min(min(ak2, o2), max(ak1, o1)); ak1 = min(ak1, o1);
        o1 = (uint32_t)__shfl_xor((int)bk1, off);
        o2 = (uint32_t)__shfl_xor((int)bk2, off);
        bk2 = min(min(bk2, o2), max(bk1, o1)); bk1 = min(bk1, o1);
    }
    if (part == 0) {
        {
            const float d1 = __uint_as_float(ak1 & QMASK);
            const float d2 = __uint_as_float(ak2 & QMASK);
            idx16[n0] = (uint16_t)(ak1 & IMASK);
            if (d2 - d1 < fmaf(0.004f, d1, 1e-4f)) {   // covers quantum + f32 err
                uint32_t p = atomicAdd(count, 1u); list16[p] = (uint16_t)n0;
            }
        }
        {
            const float d1 = __uint_as_float(bk1 & QMASK);
            const float d2 = __uint_as_float(bk2 & QMASK);
            idx16[n0+1] = (uint16_t)(bk1 & IMASK);
            if (d2 - d1 < fmaf(0.004f, d1, 1e-4f)) {
                uint32_t p = atomicAdd(count, 1u); list16[p] = (uint16_t)(n0+1);
            }
        }
    }
}

// ---- K3: exact f64 argmin rescan for flagged (near-tie) points ------------
__global__ __launch_bounds__(256) void refine_kernel(
    const float* __restrict__ pts, const float* __restrict__ verts,
    const uint16_t* __restrict__ list16, const uint32_t* __restrict__ count,
    uint16_t* __restrict__ idx16)
{
    __shared__ double sd[4];
    __shared__ uint32_t si[4];
    const uint32_t cnt = *count;
    for (uint32_t j = blockIdx.x; j < cnt; j += gridDim.x) {
        const int n = (int)list16[j];
        const double px = (double)pts[n*3+0];
        const double py = (double)pts[n*3+1];
        const double pz = (double)pts[n*3+2];
        double best = 1e300; uint32_t bi = 0xFFFFFFFFu;
        for (int v = threadIdx.x; v < NV; v += 256) {
            const double dx = px - (double)verts[v*3+0];
            const double dy = py - (double)verts[v*3+1];
            const double dz = pz - (double)verts[v*3+2];
            const double d = dx*dx + dy*dy + dz*dz;
            if (d < best || (d == best && (uint32_t)v < bi)) { best = d; bi = (uint32_t)v; }
        }
        #pragma unroll
        for (int off = 1; off < 64; off <<= 1) {
            const double od = __shfl_xor(best, off);
            const uint32_t oi = (uint32_t)__shfl_xor((int)bi, off);
            if (od < best || (od == best && oi < bi)) { best = od; bi = oi; }
        }
        if ((threadIdx.x & 63) == 0) { sd[threadIdx.x >> 6] = best; si[threadIdx.x >> 6] = bi; }
        __syncthreads();
        if (threadIdx.x == 0) {
            for (int k = 1; k < 4; ++k)
                if (sd[k] < best || (sd[k] == best && si[k] < bi)) { best = sd[k]; bi = si[k]; }
            idx16[n] = (uint16_t)bi;
        }
        __syncthreads();
    }
}

// ---- K4: gather T, branchless f64 cofactor inverse, transform, dirs -------
__global__ __launch_bounds__(256) void output_kernel(
    const float* __restrict__ pts, const float* __restrict__ Ts,
    const uint16_t* __restrict__ idx16, float* __restrict__ out)
{
    __shared__ double sc[256][3];
    const int tid = threadIdx.x;
    const int n = blockIdx.x * 256 + tid;    // block = 8 whole rays
    const float px = pts[n*3+0], py = pts[n*3+1], pz = pts[n*3+2];
    const int v = (int)idx16[n];

    double m[16], inv[16];
    #pragma unroll
    for (int i = 0; i < 16; ++i) m[i] = (double)Ts[v*16 + i];

    // MESA-style 4x4 inverse (layout-agnostic: inv(M^T) = inv(M)^T)
    inv[0]  =  m[5]*m[10]*m[15] - m[5]*m[11]*m[14] - m[9]*m[6]*m[15] + m[9]*m[7]*m[14] + m[13]*m[6]*m[11] - m[13]*m[7]*m[10];
    inv[4]  = -m[4]*m[10]*m[15] + m[4]*m[11]*m[14] + m[8]*m[6]*m[15] - m[8]*m[7]*m[14] - m[12]*m[6]*m[11] + m[12]*m[7]*m[10];
    inv[8]  =  m[4]*m[9]*m[15] - m[4]*m[11]*m[13] - m[8]*m[5]*m[15] + m[8]*m[7]*m[13] + m[12]*m[5]*m[11] - m[12]*m[7]*m[9];
    inv[12] = -m[4]*m[9]*m[14] + m[4]*m[10]*m[13] + m[8]*m[5]*m[14] - m[8]*m[6]*m[13] - m[12]*m[5]*m[10] + m[12]*m[6]*m[9];
    inv[1]  = -m[1]*m[10]*m[15] + m[1]*m[11]*m[14] + m[9]*m[2]*m[15] - m[9]*m[3]*m[14] - m[13]*m[2]*m[11] + m[13]*m[3]*m[10];
    inv[5]  =  m[0]*m[10]*m[15] - m[0]*m[11]*m[14] - m[8]*m[2]*m[15] + m[8]*m[3]*m[14] + m[12]*m[2]*m[11] - m[12]*m[3]*m[10];
    inv[9]  = -m[0]*m[9]*m[15] + m[0]*m[11]*m[13] + m[8]*m[1]*m[15] - m[8]*m[3]*m[13] - m[12]*m[1]*m[11] + m[12]*m[3]*m[9];
    inv[13] =  m[0]*m[9]*m[14] - m[0]*m[10]*m[13] - m[8]*m[1]*m[14] + m[8]*m[2]*m[13] + m[12]*m[1]*m[10] - m[12]*m[2]*m[9];
    inv[2]  =  m[1]*m[6]*m[15] - m[1]*m[7]*m[14] - m[5]*m[2]*m[15] + m[5]*m[3]*m[14] + m[13]*m[2]*m[7] - m[13]*m[3]*m[6];
    inv[6]  = -m[0]*m[6]*m[15] + m[0]*m[7]*m[14] + m[4]*m[2]*m[15] - m[4]*m[3]*m[14] - m[12]*m[2]*m[7] + m[12]*m[3]*m[6];
    inv[10] =  m[0]*m[5]*m[15] - m[0]*m[7]*m[13] - m[4]*m[1]*m[15] + m[4]*m[3]*m[13] + m[12]*m[1]*m[7] - m[12]*m[3]*m[5];
    inv[14] = -m[0]*m[5]*m[14] + m[0]*m[6]*m[13] + m[4]*m[1]*m[14] - m[4]*m[2]*m[13] - m[12]*m[1]*m[6] + m[12]*m[2]*m[5];
    inv[3]  = -m[1]*m[6]*m[11] + m[1]*m[7]*m[10] + m[5]*m[2]*m[11] - m[5]*m[3]*m[10] - m[9]*m[2]*m[7] + m[9]*m[3]*m[6];
    inv[7]  =  m[0]*m[6]*m[11] - m[0]*m[7]*m[10] - m[4]*m[2]*m[11] + m[4]*m[3]*m[10] + m[8]*m[2]*m[7] - m[8]*m[3]*m[6];
    inv[11] = -m[0]*m[5]*m[11] + m[0]*m[7]*m[9] + m[4]*m[1]*m[11] - m[4]*m[3]*m[9] - m[8]*m[1]*m[7] + m[8]*m[3]*m[5];
    inv[15] =  m[0]*m[5]*m[10] - m[0]*m[6]*m[9] - m[4]*m[1]*m[10] + m[4]*m[2]*m[9] + m[8]*m[1]*m[6] - m[8]*m[2]*m[5];
    const double det = m[0]*inv[0] + m[1]*inv[4] + m[2]*inv[8] + m[3]*inv[12];
    const double rd = 1.0 / det;

    const double hx = -(double)px, hy = -(double)py, hz = (double)pz;
    const double c0 = (inv[0]*hx + inv[1]*hy + inv[2]*hz  + inv[3])  * rd;
    const double c1 = (inv[4]*hx + inv[5]*hy + inv[6]*hz  + inv[7])  * rd;
    const double c2 = (inv[8]*hx + inv[9]*hy + inv[10]*hz + inv[11]) * rd;
    const double f0 = -c0, f1 = -c1, f2 = c2;   // can * [-1,-1,1]

    out[n*3+0] = (float)f0; out[n*3+1] = (float)f1; out[n*3+2] = (float)f2;
    sc[tid][0] = f0; sc[tid][1] = f1; sc[tid][2] = f2;
    __syncthreads();

    int l0 = tid, l1 = tid + 1;
    if ((tid & (N_SAMPLES - 1)) == N_SAMPLES - 1) { l0 = tid - 1; l1 = tid; }
    const double dx = sc[l1][0] - sc[l0][0];
    const double dy = sc[l1][1] - sc[l0][1];
    const double dz = sc[l1][2] - sc[l0][2];
    const double nr = fmax(sqrt(dx*dx + dy*dy + dz*dz), 1e-12);
    float* o = out + (size_t)NPTS * 3 + (size_t)n * 3;
    o[0] = (float)(dx / nr); o[1] = (float)(dy / nr); o[2] = (float)(dz / nr);
}

// ---- launch ----------------------------------------------------------------
extern "C" void kernel_launch(void* const* d_in, const int* in_sizes, int n_in,
                              void* d_out, int out_size, void* d_ws, size_t ws_size,
                              hipStream_t stream) {
    const float* pts   = (const float*)d_in[0];   // rays_points_world
    const float* verts = (const float*)d_in[2];   // vertices_posed
    const float* Ts    = (const float*)d_in[3];   // Ts
    float* out = (float*)d_out;

    uint8_t* ws = (uint8_t*)d_ws;
    uint32_t* count  = (uint32_t*)ws;
    uint16_t* idx16  = (uint16_t*)(ws + WS_IDX_OFF);
    uint16_t* list16 = (uint16_t*)(ws + WS_LIST_OFF);

    hipLaunchKernelGGL(init_kernel,   dim3(1),         dim3(64),  0, stream, count);
    hipLaunchKernelGGL(scan_kernel,   dim3(NPTS/64),   dim3(256), 0, stream,
                       pts, verts, idx16, list16, count);
    hipLaunchKernelGGL(refine_kernel, dim3(1024),      dim3(256), 0, stream,
                       pts, verts, list16, count, idx16);
    hipLaunchKernelGGL(output_kernel, dim3(NPTS/256),  dim3(256), 0, stream,
                       pts, Ts, idx16, out);
}